// Round 1
// baseline (678.178 us; speedup 1.0000x reference)
//
#include <hip/hip_runtime.h>
#include <hip/hip_bf16.h>
#include <math.h>

typedef __attribute__((ext_vector_type(8))) short bf16x8;
typedef __attribute__((ext_vector_type(4))) float f32x4;

#define GLB_CAST(p) ((const __attribute__((address_space(1))) void*)(p))
#define LDS_CAST(p) ((__attribute__((address_space(3))) void*)(p))

// ---------------- fp32 -> bf16 convert (vectorized) ----------------
__global__ void cvt_f32_bf16(const float* __restrict__ s, __hip_bfloat16* __restrict__ d, int n) {
    int i = (blockIdx.x * 256 + threadIdx.x) * 8;
    if (i >= n) return;
    float4 a = *(const float4*)(s + i);
    float4 b = *(const float4*)(s + i + 4);
    float t[8] = {a.x, a.y, a.z, a.w, b.x, b.y, b.z, b.w};
    union { unsigned short u[8]; uint4 v; } o;
#pragma unroll
    for (int j = 0; j < 8; ++j) {
        __hip_bfloat16 h = __float2bfloat16(t[j]);
        o.u[j] = *(unsigned short*)&h;
    }
    *(uint4*)(d + i) = o.v;
}

// ---------------- bf16 GEMM: C[m,n] = sum_k A[m,k] * Bt[n,k] ----------------
// M=4096, N=2048, K=2048 fixed. 128x128 tile, BK=32, 4 waves (2x2), m97 structure.
// EPI 0: bf16 out scattered to [B*H][S][hd] (B=2,S=2048,H=16,hd=128)
// EPI 1: fp32 out row-major [M][N]
template <int EPI>
__global__ __launch_bounds__(256, 2)
void gemm_bt(const __hip_bfloat16* __restrict__ A,
             const __hip_bfloat16* __restrict__ Bt,
             void* __restrict__ Cout)
{
    const int K = 2048;
    __shared__ __hip_bfloat16 As[128 * 32];
    __shared__ __hip_bfloat16 Bs[128 * 32];
    const int tid = threadIdx.x;
    const int w = tid >> 6, l = tid & 63;
    const int m0 = blockIdx.x * 128, n0 = blockIdx.y * 128;
    const int wr = w >> 1, wc = w & 1;
    const int lr = l & 15, kh = l >> 4;

    f32x4 acc[4][4] = {};

    for (int kt = 0; kt < 64; ++kt) {
        const int kb = kt * 32;
#pragma unroll
        for (int i = 0; i < 2; ++i) {
            const int s = i * 256 + tid;
            const int r = s >> 2, ks = (s & 3) * 8;
            __builtin_amdgcn_global_load_lds(GLB_CAST(A + (size_t)(m0 + r) * K + kb + ks),
                                             LDS_CAST(As + (size_t)(i * 256 + w * 64) * 8),
                                             16, 0, 0);
            __builtin_amdgcn_global_load_lds(GLB_CAST(Bt + (size_t)(n0 + r) * K + kb + ks),
                                             LDS_CAST(Bs + (size_t)(i * 256 + w * 64) * 8),
                                             16, 0, 0);
        }
        __syncthreads();
        bf16x8 af[4], bfr[4];
#pragma unroll
        for (int m = 0; m < 4; ++m)
            af[m] = *(const bf16x8*)(As + (wr * 64 + m * 16 + lr) * 32 + kh * 8);
#pragma unroll
        for (int n = 0; n < 4; ++n)
            bfr[n] = *(const bf16x8*)(Bs + (wc * 64 + n * 16 + lr) * 32 + kh * 8);
#pragma unroll
        for (int m = 0; m < 4; ++m)
#pragma unroll
            for (int n = 0; n < 4; ++n)
                acc[m][n] = __builtin_amdgcn_mfma_f32_16x16x32_bf16(af[m], bfr[n], acc[m][n], 0, 0, 0);
        __syncthreads();
    }

#pragma unroll
    for (int m = 0; m < 4; ++m) {
        const int r0 = m0 + wr * 64 + m * 16 + kh * 4;
#pragma unroll
        for (int n = 0; n < 4; ++n) {
            const int c = n0 + wc * 64 + n * 16 + lr;
#pragma unroll
            for (int j = 0; j < 4; ++j) {
                const int r = r0 + j;
                const float v = acc[m][n][j];
                if (EPI == 0) {
                    const int b = r >> 11, sy = r & 2047, h = c >> 7, dd = c & 127;
                    ((__hip_bfloat16*)Cout)[((size_t)(b * 16 + h) * 2048 + sy) * 128 + dd] =
                        __float2bfloat16(v);
                } else {
                    ((float*)Cout)[(size_t)r * 2048 + c] = v;
                }
            }
        }
    }
}

// ---------------- RoPE in-place on Q and K: [32][2048][128] ----------------
__global__ void rope_qk(__hip_bfloat16* __restrict__ Q, __hip_bfloat16* __restrict__ Kk) {
    const int row = blockIdx.x * 4 + (threadIdx.x >> 6);
    const int j = threadIdx.x & 63;
    const int s = row & 2047;
    const float inv = expf((float)j * (-0.14391156831212787f)); // -ln(10000)/64
    float sn, c;
    sincosf((float)s * inv, &sn, &c);
    const size_t base = (size_t)row * 128;
    float q1 = __bfloat162float(Q[base + j]);
    float q2 = __bfloat162float(Q[base + 64 + j]);
    Q[base + j]      = __float2bfloat16(q1 * c - q2 * sn);
    Q[base + 64 + j] = __float2bfloat16(q2 * c + q1 * sn);
    float k1 = __bfloat162float(Kk[base + j]);
    float k2 = __bfloat162float(Kk[base + 64 + j]);
    Kk[base + j]      = __float2bfloat16(k1 * c - k2 * sn);
    Kk[base + 64 + j] = __float2bfloat16(k2 * c + k1 * sn);
}

// ---------------- V transpose: [32][2048][128] -> [32][128][2048] ----------------
__global__ void transpose_v(const __hip_bfloat16* __restrict__ V, __hip_bfloat16* __restrict__ Vt) {
    __shared__ __hip_bfloat16 t[32][33];
    const int bh = blockIdx.z;
    const int s0 = blockIdx.x * 32, d0 = blockIdx.y * 32;
    const __hip_bfloat16* Vb = V + (size_t)bh * 2048 * 128;
    __hip_bfloat16* Vtb = Vt + (size_t)bh * 128 * 2048;
    const int tx = threadIdx.x, ty = threadIdx.y;
#pragma unroll
    for (int i = 0; i < 32; i += 8)
        t[ty + i][tx] = Vb[(size_t)(s0 + ty + i) * 128 + d0 + tx];
    __syncthreads();
#pragma unroll
    for (int i = 0; i < 32; i += 8)
        Vtb[(size_t)(d0 + ty + i) * 2048 + s0 + tx] = t[tx][ty + i];
}

// ---------------- causal flash attention ----------------
// Q,K: [32][2048][128] bf16 (post-RoPE). Vt: [32][128][2048] bf16.
// AO: [B=2][S=2048][H=16][hd=128] bf16 (= [4096][2048] row-major).
// 4 independent waves/block; wave owns 16 q rows; KV tiles of 32.
__global__ __launch_bounds__(256, 2)
void flash_attn(const __hip_bfloat16* __restrict__ Q,
                const __hip_bfloat16* __restrict__ K,
                const __hip_bfloat16* __restrict__ Vt,
                __hip_bfloat16* __restrict__ AO)
{
    const int bh = blockIdx.y;
    const int qtile = gridDim.x - 1 - blockIdx.x;  // heavy tiles first
    const int tid = threadIdx.x, w = tid >> 6, l = tid & 63;
    const int lr = l & 15, hi = l >> 4;
    const int qb = qtile * 64 + w * 16;

    const __hip_bfloat16* Qb = Q + (size_t)bh * 2048 * 128;
    const __hip_bfloat16* Kb = K + (size_t)bh * 2048 * 128;
    const __hip_bfloat16* Vb = Vt + (size_t)bh * 128 * 2048;

    // Q fragments (A-layout: row = lr, k = kk*32 + hi*8 + j)
    bf16x8 qf[4];
#pragma unroll
    for (int kk = 0; kk < 4; ++kk)
        qf[kk] = *(const bf16x8*)(Qb + (size_t)(qb + lr) * 128 + kk * 32 + hi * 8);

    f32x4 o[8] = {};
    float mrow[4] = {-1e30f, -1e30f, -1e30f, -1e30f};
    float lrow[4] = {0.f, 0.f, 0.f, 0.f};

    __shared__ __hip_bfloat16 Pl[4][16 * 40];  // per-wave P buffer, stride 40 (conflict pad)
    __hip_bfloat16* Pw = &Pl[w][0];

    const float scale = 0.08838834764831845f;  // 1/sqrt(128)
    const int ntiles = (qb + 16 + 31) >> 5;

    for (int kvt = 0; kvt < ntiles; ++kvt) {
        const int kv0 = kvt * 32;
        // S = Q K^T : two 16-col fragments
        f32x4 sf[2] = {};
#pragma unroll
        for (int f = 0; f < 2; ++f)
#pragma unroll
            for (int kk = 0; kk < 4; ++kk) {
                bf16x8 kf = *(const bf16x8*)(Kb + (size_t)(kv0 + f * 16 + lr) * 128 + kk * 32 + hi * 8);
                sf[f] = __builtin_amdgcn_mfma_f32_16x16x32_bf16(qf[kk], kf, sf[f], 0, 0, 0);
            }

        float alpha[4];
#pragma unroll
        for (int j = 0; j < 4; ++j) {
            const int q = qb + hi * 4 + j;
            float s0v = sf[0][j] * scale; if (kv0 + lr > q)      s0v = -1e30f;
            float s1v = sf[1][j] * scale; if (kv0 + 16 + lr > q) s1v = -1e30f;
            float mx = fmaxf(s0v, s1v);
#pragma unroll
            for (int dd = 1; dd < 16; dd <<= 1)
                mx = fmaxf(mx, __shfl_xor(mx, dd));
            const float mnew = fmaxf(mrow[j], mx);
            alpha[j] = __expf(mrow[j] - mnew);
            mrow[j] = mnew;
            const float p0 = __expf(s0v - mnew);
            const float p1 = __expf(s1v - mnew);
            float rs = p0 + p1;
#pragma unroll
            for (int dd = 1; dd < 16; dd <<= 1)
                rs += __shfl_xor(rs, dd);
            lrow[j] = lrow[j] * alpha[j] + rs;
            Pw[(hi * 4 + j) * 40 + lr]      = __float2bfloat16(p0);
            Pw[(hi * 4 + j) * 40 + 16 + lr] = __float2bfloat16(p1);
        }
        // rescale O
#pragma unroll
        for (int dn = 0; dn < 8; ++dn)
#pragma unroll
            for (int j = 0; j < 4; ++j) o[dn][j] *= alpha[j];

        // PV: A = P (row = lr, k = hi*8+j), B = V^T rows (col = dn*16+lr, k = kv)
        const bf16x8 pf = *(const bf16x8*)(Pw + lr * 40 + hi * 8);
#pragma unroll
        for (int dn = 0; dn < 8; ++dn) {
            const bf16x8 vf = *(const bf16x8*)(Vb + (size_t)(dn * 16 + lr) * 2048 + kv0 + hi * 8);
            o[dn] = __builtin_amdgcn_mfma_f32_16x16x32_bf16(pf, vf, o[dn], 0, 0, 0);
        }
    }

    // normalize + store
#pragma unroll
    for (int j = 0; j < 4; ++j) {
        const float inv = 1.0f / lrow[j];
        const int q = qb + hi * 4 + j;
        const size_t rb = ((size_t)(bh >> 4) * 2048 + q) * 2048 + (size_t)(bh & 15) * 128;
#pragma unroll
        for (int dn = 0; dn < 8; ++dn)
            AO[rb + dn * 16 + lr] = __float2bfloat16(o[dn][j] * inv);
    }
}

extern "C" void kernel_launch(void* const* d_in, const int* in_sizes, int n_in,
                              void* d_out, int out_size, void* d_ws, size_t ws_size,
                              hipStream_t stream) {
    (void)in_sizes; (void)n_in; (void)out_size; (void)ws_size;
    const float* x  = (const float*)d_in[0];
    const float* Wq = (const float*)d_in[1];
    const float* Wk = (const float*)d_in[2];
    const float* Wv = (const float*)d_in[3];
    const float* Wo = (const float*)d_in[4];

    char* p = (char*)d_ws;
    auto carve = [&](size_t bytes) -> char* {
        char* r = p;
        p += (bytes + 255) & ~(size_t)255;
        return r;
    };
    __hip_bfloat16* xb  = (__hip_bfloat16*)carve(4096ull * 2048 * 2);  // reused as AO after QKV GEMMs
    __hip_bfloat16* Wqb = (__hip_bfloat16*)carve(2048ull * 2048 * 2);
    __hip_bfloat16* Wkb = (__hip_bfloat16*)carve(2048ull * 2048 * 2);
    __hip_bfloat16* Wvb = (__hip_bfloat16*)carve(2048ull * 2048 * 2);
    __hip_bfloat16* Wob = (__hip_bfloat16*)carve(2048ull * 2048 * 2);
    __hip_bfloat16* Qb  = (__hip_bfloat16*)carve(32ull * 2048 * 128 * 2);
    __hip_bfloat16* Kb  = (__hip_bfloat16*)carve(32ull * 2048 * 128 * 2);
    __hip_bfloat16* Vb  = (__hip_bfloat16*)carve(32ull * 2048 * 128 * 2);
    __hip_bfloat16* Vtb = (__hip_bfloat16*)carve(32ull * 128 * 2048 * 2);

    cvt_f32_bf16<<<4096, 256, 0, stream>>>(x,  xb,  4096 * 2048);
    cvt_f32_bf16<<<2048, 256, 0, stream>>>(Wq, Wqb, 2048 * 2048);
    cvt_f32_bf16<<<2048, 256, 0, stream>>>(Wk, Wkb, 2048 * 2048);
    cvt_f32_bf16<<<2048, 256, 0, stream>>>(Wv, Wvb, 2048 * 2048);
    cvt_f32_bf16<<<2048, 256, 0, stream>>>(Wo, Wob, 2048 * 2048);

    dim3 gg(32, 16);
    gemm_bt<0><<<gg, 256, 0, stream>>>(xb, Wqb, Qb);
    gemm_bt<0><<<gg, 256, 0, stream>>>(xb, Wkb, Kb);
    gemm_bt<0><<<gg, 256, 0, stream>>>(xb, Wvb, Vb);

    rope_qk<<<16384, 256, 0, stream>>>(Qb, Kb);
    transpose_v<<<dim3(64, 4, 32), dim3(32, 8), 0, stream>>>(Vb, Vtb);

    flash_attn<<<dim3(32, 32), 256, 0, stream>>>(Qb, Kb, Vtb, xb /* AO */);

    gemm_bt<1><<<gg, 256, 0, stream>>>(xb, Wob, (float*)d_out);
}

// Round 2
// 549.716 us; speedup vs baseline: 1.2337x; 1.2337x over previous
//
#include <hip/hip_runtime.h>
#include <hip/hip_bf16.h>
#include <math.h>

typedef __attribute__((ext_vector_type(8))) short bf16x8;
typedef __attribute__((ext_vector_type(4))) float f32x4;

#define GLB_CAST(p) ((const __attribute__((address_space(1))) void*)(p))
#define LDS_CAST(p) ((__attribute__((address_space(3))) void*)(p))

// ---------------- fp32 -> bf16 convert (vectorized) ----------------
__global__ void cvt_f32_bf16(const float* __restrict__ s, __hip_bfloat16* __restrict__ d, int n) {
    int i = (blockIdx.x * 256 + threadIdx.x) * 8;
    if (i >= n) return;
    float4 a = *(const float4*)(s + i);
    float4 b = *(const float4*)(s + i + 4);
    float t[8] = {a.x, a.y, a.z, a.w, b.x, b.y, b.z, b.w};
    union { unsigned short u[8]; uint4 v; } o;
#pragma unroll
    for (int j = 0; j < 8; ++j) {
        __hip_bfloat16 h = __float2bfloat16(t[j]);
        o.u[j] = *(unsigned short*)&h;
    }
    *(uint4*)(d + i) = o.v;
}

// ---------------- bf16 GEMM: C[m,n] = sum_k A[m,k] * Bt[n,k] ----------------
// M=4096, N=2048, K=2048 fixed. 128x128 tile, BK=32, 4 waves (2x2), m97 structure.
// EPI 0: bf16 out scattered to [B*H][S][hd] (B=2,S=2048,H=16,hd=128)
// EPI 1: fp32 out row-major [M][N]
// EPI 2: bf16 out scattered TRANSPOSED to [B*H][hd][S]  (for V)
template <int EPI>
__global__ __launch_bounds__(256, 2)
void gemm_bt(const __hip_bfloat16* __restrict__ A,
             const __hip_bfloat16* __restrict__ Bt,
             void* __restrict__ Cout)
{
    const int K = 2048;
    __shared__ __hip_bfloat16 As[128 * 32];
    __shared__ __hip_bfloat16 Bs[128 * 32];
    const int tid = threadIdx.x;
    const int w = tid >> 6, l = tid & 63;
    const int m0 = blockIdx.x * 128, n0 = blockIdx.y * 128;
    const int wr = w >> 1, wc = w & 1;
    const int lr = l & 15, kh = l >> 4;

    f32x4 acc[4][4] = {};

    for (int kt = 0; kt < 64; ++kt) {
        const int kb = kt * 32;
#pragma unroll
        for (int i = 0; i < 2; ++i) {
            const int s = i * 256 + tid;
            const int r = s >> 2, ks = (s & 3) * 8;
            __builtin_amdgcn_global_load_lds(GLB_CAST(A + (size_t)(m0 + r) * K + kb + ks),
                                             LDS_CAST(As + (size_t)(i * 256 + w * 64) * 8),
                                             16, 0, 0);
            __builtin_amdgcn_global_load_lds(GLB_CAST(Bt + (size_t)(n0 + r) * K + kb + ks),
                                             LDS_CAST(Bs + (size_t)(i * 256 + w * 64) * 8),
                                             16, 0, 0);
        }
        __syncthreads();
        bf16x8 af[4], bfr[4];
#pragma unroll
        for (int m = 0; m < 4; ++m)
            af[m] = *(const bf16x8*)(As + (wr * 64 + m * 16 + lr) * 32 + kh * 8);
#pragma unroll
        for (int n = 0; n < 4; ++n)
            bfr[n] = *(const bf16x8*)(Bs + (wc * 64 + n * 16 + lr) * 32 + kh * 8);
#pragma unroll
        for (int m = 0; m < 4; ++m)
#pragma unroll
            for (int n = 0; n < 4; ++n)
                acc[m][n] = __builtin_amdgcn_mfma_f32_16x16x32_bf16(af[m], bfr[n], acc[m][n], 0, 0, 0);
        __syncthreads();
    }

#pragma unroll
    for (int m = 0; m < 4; ++m) {
        const int r0 = m0 + wr * 64 + m * 16 + kh * 4;
#pragma unroll
        for (int n = 0; n < 4; ++n) {
            const int c = n0 + wc * 64 + n * 16 + lr;
#pragma unroll
            for (int j = 0; j < 4; ++j) {
                const int r = r0 + j;
                const float v = acc[m][n][j];
                if (EPI == 0) {
                    const int b = r >> 11, sy = r & 2047, h = c >> 7, dd = c & 127;
                    ((__hip_bfloat16*)Cout)[((size_t)(b * 16 + h) * 2048 + sy) * 128 + dd] =
                        __float2bfloat16(v);
                } else if (EPI == 2) {
                    const int b = r >> 11, sy = r & 2047, h = c >> 7, dd = c & 127;
                    ((__hip_bfloat16*)Cout)[((size_t)(b * 16 + h) * 128 + dd) * 2048 + sy] =
                        __float2bfloat16(v);
                } else {
                    ((float*)Cout)[(size_t)r * 2048 + c] = v;
                }
            }
        }
    }
}

// ---------------- RoPE in-place on Q and K: [32][2048][128] ----------------
__global__ void rope_qk(__hip_bfloat16* __restrict__ Q, __hip_bfloat16* __restrict__ Kk) {
    const int row = blockIdx.x * 4 + (threadIdx.x >> 6);
    const int j = threadIdx.x & 63;
    const int s = row & 2047;
    const float inv = expf((float)j * (-0.14391156831212787f)); // -ln(10000)/64
    float sn, c;
    sincosf((float)s * inv, &sn, &c);
    const size_t base = (size_t)row * 128;
    float q1 = __bfloat162float(Q[base + j]);
    float q2 = __bfloat162float(Q[base + 64 + j]);
    Q[base + j]      = __float2bfloat16(q1 * c - q2 * sn);
    Q[base + 64 + j] = __float2bfloat16(q2 * c + q1 * sn);
    float k1 = __bfloat162float(Kk[base + j]);
    float k2 = __bfloat162float(Kk[base + 64 + j]);
    Kk[base + j]      = __float2bfloat16(k1 * c - k2 * sn);
    Kk[base + 64 + j] = __float2bfloat16(k2 * c + k1 * sn);
}

// ---------------- causal flash attention, balanced pieces ----------------
// Q,K: [32][2048][128] bf16 (post-RoPE). Vt: [32][128][2048] bf16.
// AO: [B=2][S=2048][H=16][hd=128] bf16 (= [4096][2048] row-major).
// Work item = one wave = (16 q-rows, KV tile subrange).
//   groups g=0..127 (16 rows each), ntiles(g) = g/2+1 (KV tiles of 32).
//   g<64  : 1 piece, finalize directly to AO.
//   g>=64 : 2 pieces (tiles [0,mid) and [mid,nt)), write partials OP/ML.
// wave id u = blockIdx.x*4 + w, u 0..191 per bh, heavy pieces at low u.
__global__ __launch_bounds__(256, 2)
void flash_part(const __hip_bfloat16* __restrict__ Q,
                const __hip_bfloat16* __restrict__ K,
                const __hip_bfloat16* __restrict__ Vt,
                __hip_bfloat16* __restrict__ AO,
                __hip_bfloat16* __restrict__ OP,
                float* __restrict__ ML)
{
    const int bh = blockIdx.y;
    const int tid = threadIdx.x, w = tid >> 6, l = tid & 63;
    const int lr = l & 15, hi = l >> 4;
    const int u = blockIdx.x * 4 + w;

    int g, t0, t1, half;
    bool split;
    if (u < 128) {                 // split pieces, g = 127 .. 64
        g = 127 - (u >> 1);
        half = u & 1;
        const int nt = (g >> 1) + 1;
        const int mid = nt >> 1;
        t0 = half ? mid : 0;
        t1 = half ? nt : mid;
        split = true;
    } else {                       // whole groups, g = 63 .. 0
        g = 191 - u;
        half = 0;
        t0 = 0;
        t1 = (g >> 1) + 1;
        split = false;
    }
    const int qb = g * 16;

    const __hip_bfloat16* Qb = Q  + (size_t)bh * 2048 * 128;
    const __hip_bfloat16* Kb = K  + (size_t)bh * 2048 * 128;
    const __hip_bfloat16* Vb = Vt + (size_t)bh * 128 * 2048;

    // Q fragments (A-layout: row = lr, k = kk*32 + hi*8 + j)
    bf16x8 qf[4];
#pragma unroll
    for (int kk = 0; kk < 4; ++kk)
        qf[kk] = *(const bf16x8*)(Qb + (size_t)(qb + lr) * 128 + kk * 32 + hi * 8);

    f32x4 o[8] = {};
    float mrow[4] = {-1e30f, -1e30f, -1e30f, -1e30f};
    float lrow[4] = {0.f, 0.f, 0.f, 0.f};

    __shared__ __hip_bfloat16 Pl[4][16 * 40];  // per-wave P buffer, stride 40 (conflict pad)
    __hip_bfloat16* Pw = &Pl[w][0];

    const float scale = 0.08838834764831845f;  // 1/sqrt(128)

    for (int kvt = t0; kvt < t1; ++kvt) {
        const int kv0 = kvt * 32;
        // S = Q K^T : two 16-col fragments
        f32x4 sf[2] = {};
#pragma unroll
        for (int f = 0; f < 2; ++f)
#pragma unroll
            for (int kk = 0; kk < 4; ++kk) {
                bf16x8 kf = *(const bf16x8*)(Kb + (size_t)(kv0 + f * 16 + lr) * 128 + kk * 32 + hi * 8);
                sf[f] = __builtin_amdgcn_mfma_f32_16x16x32_bf16(qf[kk], kf, sf[f], 0, 0, 0);
            }

        float alpha[4];
#pragma unroll
        for (int j = 0; j < 4; ++j) {
            const int q = qb + hi * 4 + j;
            float s0v = sf[0][j] * scale; if (kv0 + lr > q)      s0v = -1e30f;
            float s1v = sf[1][j] * scale; if (kv0 + 16 + lr > q) s1v = -1e30f;
            float mx = fmaxf(s0v, s1v);
#pragma unroll
            for (int dd = 1; dd < 16; dd <<= 1)
                mx = fmaxf(mx, __shfl_xor(mx, dd));
            const float mnew = fmaxf(mrow[j], mx);
            alpha[j] = __expf(mrow[j] - mnew);
            mrow[j] = mnew;
            const float p0 = __expf(s0v - mnew);
            const float p1 = __expf(s1v - mnew);
            float rs = p0 + p1;
#pragma unroll
            for (int dd = 1; dd < 16; dd <<= 1)
                rs += __shfl_xor(rs, dd);
            lrow[j] = lrow[j] * alpha[j] + rs;
            Pw[(hi * 4 + j) * 40 + lr]      = __float2bfloat16(p0);
            Pw[(hi * 4 + j) * 40 + 16 + lr] = __float2bfloat16(p1);
        }
        // rescale O
#pragma unroll
        for (int dn = 0; dn < 8; ++dn)
#pragma unroll
            for (int j = 0; j < 4; ++j) o[dn][j] *= alpha[j];

        // PV: A = P (row = lr, k = hi*8+j), B = V^T rows (col = dn*16+lr, k = kv)
        const bf16x8 pf = *(const bf16x8*)(Pw + lr * 40 + hi * 8);
#pragma unroll
        for (int dn = 0; dn < 8; ++dn) {
            const bf16x8 vf = *(const bf16x8*)(Vb + (size_t)(dn * 16 + lr) * 2048 + kv0 + hi * 8);
            o[dn] = __builtin_amdgcn_mfma_f32_16x16x32_bf16(pf, vf, o[dn], 0, 0, 0);
        }
    }

    if (!split) {
        // normalize + store to AO
#pragma unroll
        for (int j = 0; j < 4; ++j) {
            const float inv = 1.0f / lrow[j];
            const int q = qb + hi * 4 + j;
            const size_t rb = ((size_t)(bh >> 4) * 2048 + q) * 2048 + (size_t)(bh & 15) * 128;
#pragma unroll
            for (int dn = 0; dn < 8; ++dn)
                AO[rb + dn * 16 + lr] = __float2bfloat16(o[dn][j] * inv);
        }
    } else {
        // write unnormalized partial + (m, l)
        const int p = (bh * 64 + (g - 64)) * 2 + half;
#pragma unroll
        for (int j = 0; j < 4; ++j) {
            const int row = hi * 4 + j;
#pragma unroll
            for (int dn = 0; dn < 8; ++dn)
                OP[(size_t)p * 2048 + row * 128 + dn * 16 + lr] = __float2bfloat16(o[dn][j]);
            if (lr == 0) {
                ML[p * 32 + row * 2]     = mrow[j];
                ML[p * 32 + row * 2 + 1] = lrow[j];
            }
        }
    }
}

// ---------------- merge the two partials of each split group ----------------
__global__ void flash_merge(const __hip_bfloat16* __restrict__ OP,
                            const float* __restrict__ ML,
                            __hip_bfloat16* __restrict__ AO)
{
    const int sg = blockIdx.x & 63, bh = blockIdx.x >> 6;
    const int g = 64 + sg;
    const int tid = threadIdx.x;
    const int row = tid >> 4;
    const int c0 = (tid & 15) * 8;
    const int p0 = (bh * 64 + sg) * 2;

    const float m1 = ML[p0 * 32 + row * 2],       l1 = ML[p0 * 32 + row * 2 + 1];
    const float m2 = ML[(p0 + 1) * 32 + row * 2], l2 = ML[(p0 + 1) * 32 + row * 2 + 1];
    const float M  = fmaxf(m1, m2);
    const float c1 = __expf(m1 - M), c2 = __expf(m2 - M);
    const float inv = 1.0f / (l1 * c1 + l2 * c2);

    const bf16x8 av = *(const bf16x8*)(OP + ((size_t)p0 * 16 + row) * 128 + c0);
    const bf16x8 bv = *(const bf16x8*)(OP + ((size_t)(p0 + 1) * 16 + row) * 128 + c0);

    const int q = g * 16 + row;
    __hip_bfloat16* out = AO + ((size_t)(bh >> 4) * 2048 + q) * 2048 + (size_t)(bh & 15) * 128 + c0;

    union { unsigned short us[8]; bf16x8 v; } r;
#pragma unroll
    for (int i = 0; i < 8; ++i) {
        __hip_bfloat16 ah, bh2;
        *(short*)&ah  = av[i];
        *(short*)&bh2 = bv[i];
        const float val = (__bfloat162float(ah) * c1 + __bfloat162float(bh2) * c2) * inv;
        __hip_bfloat16 hv = __float2bfloat16(val);
        r.us[i] = *(unsigned short*)&hv;
    }
    *(bf16x8*)out = r.v;
}

extern "C" void kernel_launch(void* const* d_in, const int* in_sizes, int n_in,
                              void* d_out, int out_size, void* d_ws, size_t ws_size,
                              hipStream_t stream) {
    (void)in_sizes; (void)n_in; (void)out_size; (void)ws_size;
    const float* x  = (const float*)d_in[0];
    const float* Wq = (const float*)d_in[1];
    const float* Wk = (const float*)d_in[2];
    const float* Wv = (const float*)d_in[3];
    const float* Wo = (const float*)d_in[4];

    char* p = (char*)d_ws;
    auto carve = [&](size_t bytes) -> char* {
        char* r = p;
        p += (bytes + 255) & ~(size_t)255;
        return r;
    };
    __hip_bfloat16* xb  = (__hip_bfloat16*)carve(4096ull * 2048 * 2);  // reused as AO after QKV GEMMs
    __hip_bfloat16* Wqb = (__hip_bfloat16*)carve(2048ull * 2048 * 2);
    __hip_bfloat16* Wkb = (__hip_bfloat16*)carve(2048ull * 2048 * 2);
    __hip_bfloat16* Wvb = (__hip_bfloat16*)carve(2048ull * 2048 * 2);
    __hip_bfloat16* Wob = (__hip_bfloat16*)carve(2048ull * 2048 * 2);
    __hip_bfloat16* Qb  = (__hip_bfloat16*)carve(32ull * 2048 * 128 * 2);
    __hip_bfloat16* Kb  = (__hip_bfloat16*)carve(32ull * 2048 * 128 * 2);
    __hip_bfloat16* Vtb = (__hip_bfloat16*)carve(32ull * 128 * 2048 * 2);
    __hip_bfloat16* OPb = (__hip_bfloat16*)carve(4096ull * 16 * 128 * 2);  // partial O
    float*          MLb = (float*)carve(4096ull * 32 * 4);                 // partial m,l

    cvt_f32_bf16<<<4096, 256, 0, stream>>>(x,  xb,  4096 * 2048);
    cvt_f32_bf16<<<2048, 256, 0, stream>>>(Wq, Wqb, 2048 * 2048);
    cvt_f32_bf16<<<2048, 256, 0, stream>>>(Wk, Wkb, 2048 * 2048);
    cvt_f32_bf16<<<2048, 256, 0, stream>>>(Wv, Wvb, 2048 * 2048);
    cvt_f32_bf16<<<2048, 256, 0, stream>>>(Wo, Wob, 2048 * 2048);

    dim3 gg(32, 16);
    gemm_bt<0><<<gg, 256, 0, stream>>>(xb, Wqb, Qb);
    gemm_bt<0><<<gg, 256, 0, stream>>>(xb, Wkb, Kb);
    gemm_bt<2><<<gg, 256, 0, stream>>>(xb, Wvb, Vtb);

    rope_qk<<<16384, 256, 0, stream>>>(Qb, Kb);

    flash_part<<<dim3(48, 32), 256, 0, stream>>>(Qb, Kb, Vtb, xb /* AO */, OPb, MLb);
    flash_merge<<<2048, 256, 0, stream>>>(OPb, MLb, xb /* AO */);

    gemm_bt<1><<<gg, 256, 0, stream>>>(xb, Wob, (float*)d_out);
}

// Round 3
// 356.179 us; speedup vs baseline: 1.9040x; 1.5434x over previous
//
#include <hip/hip_runtime.h>
#include <hip/hip_bf16.h>
#include <math.h>

typedef __attribute__((ext_vector_type(8))) short bf16x8;
typedef __attribute__((ext_vector_type(4))) float f32x4;

#define GLB_CAST(p) ((const __attribute__((address_space(1))) void*)(p))
#define LDS_CAST(p) ((__attribute__((address_space(3))) void*)(p))

// ---------------- fp32 -> bf16 convert (vectorized) ----------------
__global__ void cvt_f32_bf16(const float* __restrict__ s, __hip_bfloat16* __restrict__ d, int n) {
    int i = (blockIdx.x * 256 + threadIdx.x) * 8;
    if (i >= n) return;
    float4 a = *(const float4*)(s + i);
    float4 b = *(const float4*)(s + i + 4);
    float t[8] = {a.x, a.y, a.z, a.w, b.x, b.y, b.z, b.w};
    union { unsigned short u[8]; uint4 v; } o;
#pragma unroll
    for (int j = 0; j < 8; ++j) {
        __hip_bfloat16 h = __float2bfloat16(t[j]);
        o.u[j] = *(unsigned short*)&h;
    }
    *(uint4*)(d + i) = o.v;
}

// ---------------- bf16 GEMM: C[m,n] = sum_k A[m,k] * Bt[n,k] ----------------
// M=4096, N=2048, K=2048. 128x128 tile, BK=32, 4 waves, m97 structure.
// EPI 0: bf16 out scattered to [B*H][S][hd];  EPI 1: fp32 [M][N];  EPI 2: bf16 [B*H][hd][S]
template <int EPI>
__global__ __launch_bounds__(256, 2)
void gemm_bt(const __hip_bfloat16* __restrict__ A,
             const __hip_bfloat16* __restrict__ Bt,
             void* __restrict__ Cout)
{
    const int K = 2048;
    __shared__ __hip_bfloat16 As[128 * 32];
    __shared__ __hip_bfloat16 Bs[128 * 32];
    const int tid = threadIdx.x;
    const int w = tid >> 6, l = tid & 63;
    const int m0 = blockIdx.x * 128, n0 = blockIdx.y * 128;
    const int wr = w >> 1, wc = w & 1;
    const int lr = l & 15, kh = l >> 4;

    f32x4 acc[4][4] = {};

    for (int kt = 0; kt < 64; ++kt) {
        const int kb = kt * 32;
#pragma unroll
        for (int i = 0; i < 2; ++i) {
            const int s = i * 256 + tid;
            const int r = s >> 2, ks = (s & 3) * 8;
            __builtin_amdgcn_global_load_lds(GLB_CAST(A + (size_t)(m0 + r) * K + kb + ks),
                                             LDS_CAST(As + (size_t)(i * 256 + w * 64) * 8),
                                             16, 0, 0);
            __builtin_amdgcn_global_load_lds(GLB_CAST(Bt + (size_t)(n0 + r) * K + kb + ks),
                                             LDS_CAST(Bs + (size_t)(i * 256 + w * 64) * 8),
                                             16, 0, 0);
        }
        __syncthreads();
        bf16x8 af[4], bfr[4];
#pragma unroll
        for (int m = 0; m < 4; ++m)
            af[m] = *(const bf16x8*)(As + (wr * 64 + m * 16 + lr) * 32 + kh * 8);
#pragma unroll
        for (int n = 0; n < 4; ++n)
            bfr[n] = *(const bf16x8*)(Bs + (wc * 64 + n * 16 + lr) * 32 + kh * 8);
#pragma unroll
        for (int m = 0; m < 4; ++m)
#pragma unroll
            for (int n = 0; n < 4; ++n)
                acc[m][n] = __builtin_amdgcn_mfma_f32_16x16x32_bf16(af[m], bfr[n], acc[m][n], 0, 0, 0);
        __syncthreads();
    }

#pragma unroll
    for (int m = 0; m < 4; ++m) {
        const int r0 = m0 + wr * 64 + m * 16 + kh * 4;
#pragma unroll
        for (int n = 0; n < 4; ++n) {
            const int c = n0 + wc * 64 + n * 16 + lr;
#pragma unroll
            for (int j = 0; j < 4; ++j) {
                const int r = r0 + j;
                const float v = acc[m][n][j];
                if (EPI == 0) {
                    const int b = r >> 11, sy = r & 2047, h = c >> 7, dd = c & 127;
                    ((__hip_bfloat16*)Cout)[((size_t)(b * 16 + h) * 2048 + sy) * 128 + dd] =
                        __float2bfloat16(v);
                } else if (EPI == 2) {
                    const int b = r >> 11, sy = r & 2047, h = c >> 7, dd = c & 127;
                    ((__hip_bfloat16*)Cout)[((size_t)(b * 16 + h) * 128 + dd) * 2048 + sy] =
                        __float2bfloat16(v);
                } else {
                    ((float*)Cout)[(size_t)r * 2048 + c] = v;
                }
            }
        }
    }
}

// ---------------- RoPE in-place on Q and K: [32][2048][128] ----------------
__global__ void rope_qk(__hip_bfloat16* __restrict__ Q, __hip_bfloat16* __restrict__ Kk) {
    const int row = blockIdx.x * 4 + (threadIdx.x >> 6);
    const int j = threadIdx.x & 63;
    const int s = row & 2047;
    const float inv = expf((float)j * (-0.14391156831212787f)); // -ln(10000)/64
    float sn, c;
    sincosf((float)s * inv, &sn, &c);
    const size_t base = (size_t)row * 128;
    float q1 = __bfloat162float(Q[base + j]);
    float q2 = __bfloat162float(Q[base + 64 + j]);
    Q[base + j]      = __float2bfloat16(q1 * c - q2 * sn);
    Q[base + 64 + j] = __float2bfloat16(q2 * c + q1 * sn);
    float k1 = __bfloat162float(Kk[base + j]);
    float k2 = __bfloat162float(Kk[base + 64 + j]);
    Kk[base + j]      = __float2bfloat16(k1 * c - k2 * sn);
    Kk[base + 64 + j] = __float2bfloat16(k2 * c + k1 * sn);
}

// ---------------- causal flash attention: block-cooperative LDS staging ----------------
// Q,K: [32][2048][128] bf16. Vt: [32][128][2048] bf16 (V^T).
// Block = 4 waves = 64 q-rows (group G), shared KV range, KVBLK=32 double-buffered in LDS.
// Pieces: group G has nt=2G+2 tiles; G>=8 split into P in {2,3,4} pieces of <=16 tiles.
// u = blockIdx.y (slow axis -> heavy pieces dispatch first), bh = blockIdx.x.
__global__ __launch_bounds__(256, 4)
void flash_part(const __hip_bfloat16* __restrict__ Q,
                const __hip_bfloat16* __restrict__ K,
                const __hip_bfloat16* __restrict__ Vt,
                __hip_bfloat16* __restrict__ AO,
                __hip_bfloat16* __restrict__ OP,
                float* __restrict__ ML)
{
    const int bh = blockIdx.x;
    const int u  = blockIdx.y;
    const int tid = threadIdx.x, w = tid >> 6, l = tid & 63;
    const int lr = l & 15, hi = l >> 4;

    int G, part, P;
    if (u < 32)      { G = 24 + (u >> 2);            part = u & 3;       P = 4; }
    else if (u < 56) { int v = u - 32; G = 16 + v/3; part = v % 3;       P = 3; }
    else if (u < 72) { int v = u - 56; G = 8 + (v>>1); part = v & 1;     P = 2; }
    else             { G = u - 72;                   part = 0;           P = 1; }
    const int nt = 2 * G + 2;
    const int t0 = (part * nt) / P, t1 = ((part + 1) * nt) / P;
    const bool split = (P > 1);
    const int qb = G * 64 + w * 16;

    const __hip_bfloat16* Qb = Q  + (size_t)bh * 2048 * 128;
    const __hip_bfloat16* Kb = K  + (size_t)bh * 2048 * 128;
    const __hip_bfloat16* Vb = Vt + (size_t)bh * 128 * 2048;

    __shared__ __align__(16) __hip_bfloat16 Ks[2][32 * 128];
    __shared__ __align__(16) __hip_bfloat16 Vs[2][128 * 32];
    __shared__ __align__(16) __hip_bfloat16 Pl[4][16 * 40];
    __hip_bfloat16* Pw = &Pl[w][0];

    // Q fragments (A-layout: row = lr, k = kk*32 + hi*8 + j)
    bf16x8 qf[4];
#pragma unroll
    for (int kk = 0; kk < 4; ++kk)
        qf[kk] = *(const bf16x8*)(Qb + (size_t)(qb + lr) * 128 + kk * 32 + hi * 8);

    // staging geometry (per thread, loop-invariant)
    int rK[2], cK[2], rV[2], cV[2];
#pragma unroll
    for (int i = 0; i < 2; ++i) {
        const int ci = i * 4 + w;
        rK[i] = ci * 4 + (l >> 4);                 // K tile row 0..31
        cK[i] = ((l & 15) ^ (rK[i] & 7)) * 8;      // swizzled source col (elems)
        rV[i] = ci * 16 + (l >> 2);                // V^T tile row (d) 0..127
        cV[i] = ((l & 3) ^ (rV[i] & 3)) * 8;       // swizzled source col (elems)
    }
    const int rsw7 = lr & 7, vsw3 = lr & 3;

#define STAGE(buf, t)                                                                        \
    {                                                                                        \
        const int kv0_ = (t) * 32;                                                           \
        _Pragma("unroll")                                                                    \
        for (int i = 0; i < 2; ++i) {                                                        \
            __builtin_amdgcn_global_load_lds(                                                \
                GLB_CAST(Kb + (size_t)(kv0_ + rK[i]) * 128 + cK[i]),                         \
                LDS_CAST(&Ks[buf][(i * 4 + w) * 512]), 16, 0, 0);                            \
            __builtin_amdgcn_global_load_lds(                                                \
                GLB_CAST(Vb + (size_t)rV[i] * 2048 + kv0_ + cV[i]),                          \
                LDS_CAST(&Vs[buf][(i * 4 + w) * 512]), 16, 0, 0);                            \
        }                                                                                    \
    }

    f32x4 o[8] = {};
    float mrow[4] = {-1e30f, -1e30f, -1e30f, -1e30f};
    float lrow[4] = {0.f, 0.f, 0.f, 0.f};
    const float scale = 0.08838834764831845f;  // 1/sqrt(128)

    int cur = 0;
    STAGE(0, t0);
    __syncthreads();   // compiler emits vmcnt(0) drain before barrier

    for (int t = t0; t < t1; ++t) {
        if (t + 1 < t1) STAGE(cur ^ 1, t + 1);
        const __hip_bfloat16* Kc = &Ks[cur][0];
        const __hip_bfloat16* Vc = &Vs[cur][0];
        const int kv0 = t * 32;

        // S = Q K^T : two 16-col fragments, swizzled LDS reads
        f32x4 sf[2] = {};
#pragma unroll
        for (int f = 0; f < 2; ++f)
#pragma unroll
            for (int kk = 0; kk < 4; ++kk) {
                const bf16x8 kf = *(const bf16x8*)(Kc + (f * 16 + lr) * 128 +
                                                   ((kk * 4 + hi) ^ rsw7) * 8);
                sf[f] = __builtin_amdgcn_mfma_f32_16x16x32_bf16(qf[kk], kf, sf[f], 0, 0, 0);
            }

        float alpha[4];
#pragma unroll
        for (int j = 0; j < 4; ++j) {
            const int q = qb + hi * 4 + j;
            float s0v = sf[0][j] * scale; if (kv0 + lr > q)      s0v = -1e30f;
            float s1v = sf[1][j] * scale; if (kv0 + 16 + lr > q) s1v = -1e30f;
            float mx = fmaxf(s0v, s1v);
#pragma unroll
            for (int dd = 1; dd < 16; dd <<= 1)
                mx = fmaxf(mx, __shfl_xor(mx, dd));
            const float mnew = fmaxf(mrow[j], mx);
            alpha[j] = __expf(mrow[j] - mnew);
            mrow[j] = mnew;
            const float p0 = __expf(s0v - mnew);
            const float p1 = __expf(s1v - mnew);
            float rs = p0 + p1;
#pragma unroll
            for (int dd = 1; dd < 16; dd <<= 1)
                rs += __shfl_xor(rs, dd);
            lrow[j] = lrow[j] * alpha[j] + rs;
            Pw[(hi * 4 + j) * 40 + lr]      = __float2bfloat16(p0);
            Pw[(hi * 4 + j) * 40 + 16 + lr] = __float2bfloat16(p1);
        }
#pragma unroll
        for (int dn = 0; dn < 8; ++dn)
#pragma unroll
            for (int j = 0; j < 4; ++j) o[dn][j] *= alpha[j];

        // PV: A = P (row = lr, k = hi*8+j), B = V^T tile rows, swizzled LDS reads
        const bf16x8 pf = *(const bf16x8*)(Pw + lr * 40 + hi * 8);
#pragma unroll
        for (int dn = 0; dn < 8; ++dn) {
            const bf16x8 vf = *(const bf16x8*)(Vc + (dn * 16 + lr) * 32 + (hi ^ vsw3) * 8);
            o[dn] = __builtin_amdgcn_mfma_f32_16x16x32_bf16(pf, vf, o[dn], 0, 0, 0);
        }
        __syncthreads();   // drains this iter's STAGE (vmcnt) + all LDS reads
        cur ^= 1;
    }
#undef STAGE

    if (!split) {
#pragma unroll
        for (int j = 0; j < 4; ++j) {
            const float inv = 1.0f / lrow[j];
            const int q = qb + hi * 4 + j;
            const size_t rb = ((size_t)(bh >> 4) * 2048 + q) * 2048 + (size_t)(bh & 15) * 128;
#pragma unroll
            for (int dn = 0; dn < 8; ++dn)
                AO[rb + dn * 16 + lr] = __float2bfloat16(o[dn][j] * inv);
        }
    } else {
        const int base = (G < 16) ? (G - 8) * 2 : ((G < 24) ? 16 + (G - 16) * 3
                                                            : 40 + (G - 24) * 4);
        const int pidx = bh * 72 + base + part;
#pragma unroll
        for (int j = 0; j < 4; ++j) {
            const int row = w * 16 + hi * 4 + j;   // row within group, 0..63
#pragma unroll
            for (int dn = 0; dn < 8; ++dn)
                OP[((size_t)pidx * 64 + row) * 128 + dn * 16 + lr] = __float2bfloat16(o[dn][j]);
            if (lr == 0) {
                ML[((size_t)pidx * 64 + row) * 2]     = mrow[j];
                ML[((size_t)pidx * 64 + row) * 2 + 1] = lrow[j];
            }
        }
    }
}

// ---------------- merge P in {2,3,4} partials per split group ----------------
__global__ void flash_merge(const __hip_bfloat16* __restrict__ OP,
                            const float* __restrict__ ML,
                            __hip_bfloat16* __restrict__ AO)
{
    const int gi = blockIdx.x % 24, bh = blockIdx.x / 24;
    const int G = 8 + gi;
    const int P = (G < 16) ? 2 : ((G < 24) ? 3 : 4);
    const int base = (G < 16) ? (G - 8) * 2 : ((G < 24) ? 16 + (G - 16) * 3
                                                        : 40 + (G - 24) * 4);
    const int pidx0 = bh * 72 + base;
    const int t = threadIdx.x, r = t >> 2, c0 = (t & 3) * 32;

    float m[4], lv[4];
    float M = -1e30f;
#pragma unroll
    for (int p = 0; p < 4; ++p) if (p < P) {
        m[p]  = ML[((size_t)(pidx0 + p) * 64 + r) * 2];
        lv[p] = ML[((size_t)(pidx0 + p) * 64 + r) * 2 + 1];
        M = fmaxf(M, m[p]);
    }
    float wgt[4];
    float den = 0.f;
#pragma unroll
    for (int p = 0; p < 4; ++p) if (p < P) {
        wgt[p] = __expf(m[p] - M);
        den += lv[p] * wgt[p];
    }
    const float inv = 1.0f / den;

    const int q = G * 64 + r;
    __hip_bfloat16* out = AO + ((size_t)(bh >> 4) * 2048 + q) * 2048 + (size_t)(bh & 15) * 128 + c0;

#pragma unroll
    for (int ch = 0; ch < 4; ++ch) {
        float acc[8] = {0.f, 0.f, 0.f, 0.f, 0.f, 0.f, 0.f, 0.f};
#pragma unroll
        for (int p = 0; p < 4; ++p) if (p < P) {
            const bf16x8 v = *(const bf16x8*)(OP + ((size_t)(pidx0 + p) * 64 + r) * 128 + c0 + ch * 8);
#pragma unroll
            for (int i = 0; i < 8; ++i) {
                __hip_bfloat16 hv;
                *(short*)&hv = v[i];
                acc[i] += __bfloat162float(hv) * wgt[p];
            }
        }
        union { unsigned short us[8]; bf16x8 v; } rr;
#pragma unroll
        for (int i = 0; i < 8; ++i) {
            __hip_bfloat16 hv = __float2bfloat16(acc[i] * inv);
            rr.us[i] = *(unsigned short*)&hv;
        }
        *(bf16x8*)(out + ch * 8) = rr.v;
    }
}

extern "C" void kernel_launch(void* const* d_in, const int* in_sizes, int n_in,
                              void* d_out, int out_size, void* d_ws, size_t ws_size,
                              hipStream_t stream) {
    (void)in_sizes; (void)n_in; (void)out_size; (void)ws_size;
    const float* x  = (const float*)d_in[0];
    const float* Wq = (const float*)d_in[1];
    const float* Wk = (const float*)d_in[2];
    const float* Wv = (const float*)d_in[3];
    const float* Wo = (const float*)d_in[4];

    char* p = (char*)d_ws;
    auto carve = [&](size_t bytes) -> char* {
        char* r = p;
        p += (bytes + 255) & ~(size_t)255;
        return r;
    };
    __hip_bfloat16* xb  = (__hip_bfloat16*)carve(4096ull * 2048 * 2);  // reused as AO
    __hip_bfloat16* Wqb = (__hip_bfloat16*)carve(2048ull * 2048 * 2);
    __hip_bfloat16* Wkb = (__hip_bfloat16*)carve(2048ull * 2048 * 2);
    __hip_bfloat16* Wvb = (__hip_bfloat16*)carve(2048ull * 2048 * 2);
    __hip_bfloat16* Wob = (__hip_bfloat16*)carve(2048ull * 2048 * 2);
    __hip_bfloat16* Qb  = (__hip_bfloat16*)carve(32ull * 2048 * 128 * 2);
    __hip_bfloat16* Kb  = (__hip_bfloat16*)carve(32ull * 2048 * 128 * 2);
    __hip_bfloat16* Vtb = (__hip_bfloat16*)carve(32ull * 128 * 2048 * 2);
    __hip_bfloat16* OPb = (__hip_bfloat16*)carve(32ull * 72 * 64 * 128 * 2);  // partial O
    float*          MLb = (float*)carve(32ull * 72 * 64 * 2 * 4);             // partial m,l

    cvt_f32_bf16<<<4096, 256, 0, stream>>>(x,  xb,  4096 * 2048);
    cvt_f32_bf16<<<2048, 256, 0, stream>>>(Wq, Wqb, 2048 * 2048);
    cvt_f32_bf16<<<2048, 256, 0, stream>>>(Wk, Wkb, 2048 * 2048);
    cvt_f32_bf16<<<2048, 256, 0, stream>>>(Wv, Wvb, 2048 * 2048);
    cvt_f32_bf16<<<2048, 256, 0, stream>>>(Wo, Wob, 2048 * 2048);

    dim3 gg(32, 16);
    gemm_bt<0><<<gg, 256, 0, stream>>>(xb, Wqb, Qb);
    gemm_bt<0><<<gg, 256, 0, stream>>>(xb, Wkb, Kb);
    gemm_bt<2><<<gg, 256, 0, stream>>>(xb, Wvb, Vtb);

    rope_qk<<<16384, 256, 0, stream>>>(Qb, Kb);

    flash_part<<<dim3(32, 80), 256, 0, stream>>>(Qb, Kb, Vtb, xb /* AO */, OPb, MLb);
    flash_merge<<<768, 256, 0, stream>>>(OPb, MLb, xb /* AO */);

    gemm_bt<1><<<gg, 256, 0, stream>>>(xb, Wob, (float*)d_out);
}

// Round 4
// 322.473 us; speedup vs baseline: 2.1030x; 1.1045x over previous
//
#include <hip/hip_runtime.h>
#include <hip/hip_bf16.h>
#include <math.h>

typedef __attribute__((ext_vector_type(8))) short bf16x8;
typedef __attribute__((ext_vector_type(4))) float f32x4;

#define GLB_CAST(p) ((const __attribute__((address_space(1))) void*)(p))
#define LDS_CAST(p) ((__attribute__((address_space(3))) void*)(p))

static __device__ __forceinline__ unsigned short bf16_bits(float x) {
    __hip_bfloat16 h = __float2bfloat16(x);
    return *(unsigned short*)&h;
}

// ---------------- fp32 -> bf16 convert (vectorized) ----------------
__global__ void cvt_f32_bf16(const float* __restrict__ s, __hip_bfloat16* __restrict__ d, int n) {
    int i = (blockIdx.x * 256 + threadIdx.x) * 8;
    if (i >= n) return;
    float4 a = *(const float4*)(s + i);
    float4 b = *(const float4*)(s + i + 4);
    float t[8] = {a.x, a.y, a.z, a.w, b.x, b.y, b.z, b.w};
    union { unsigned short u[8]; uint4 v; } o;
#pragma unroll
    for (int j = 0; j < 8; ++j) o.u[j] = bf16_bits(t[j]);
    *(uint4*)(d + i) = o.v;
}

// ---------------- bf16 GEMM: C[m,n] = sum_k A[m,k] * Bt[n,k] ----------------
// M=4096, N=2048, K=2048. 128x128 tile, BK=32, 4 waves, m97 structure.
// EPI 0: bf16 out scattered to [B*H][S][hd];  EPI 1: fp32 [M][N];  EPI 2: bf16 [B*H][hd][S]
template <int EPI>
__global__ __launch_bounds__(256, 2)
void gemm_bt(const __hip_bfloat16* __restrict__ A,
             const __hip_bfloat16* __restrict__ Bt,
             void* __restrict__ Cout)
{
    const int K = 2048;
    __shared__ __hip_bfloat16 As[128 * 32];
    __shared__ __hip_bfloat16 Bs[128 * 32];
    const int tid = threadIdx.x;
    const int w = tid >> 6, l = tid & 63;
    const int m0 = blockIdx.x * 128, n0 = blockIdx.y * 128;
    const int wr = w >> 1, wc = w & 1;
    const int lr = l & 15, kh = l >> 4;

    f32x4 acc[4][4] = {};

    for (int kt = 0; kt < 64; ++kt) {
        const int kb = kt * 32;
#pragma unroll
        for (int i = 0; i < 2; ++i) {
            const int s = i * 256 + tid;
            const int r = s >> 2, ks = (s & 3) * 8;
            __builtin_amdgcn_global_load_lds(GLB_CAST(A + (size_t)(m0 + r) * K + kb + ks),
                                             LDS_CAST(As + (size_t)(i * 256 + w * 64) * 8),
                                             16, 0, 0);
            __builtin_amdgcn_global_load_lds(GLB_CAST(Bt + (size_t)(n0 + r) * K + kb + ks),
                                             LDS_CAST(Bs + (size_t)(i * 256 + w * 64) * 8),
                                             16, 0, 0);
        }
        __syncthreads();
        bf16x8 af[4], bfr[4];
#pragma unroll
        for (int m = 0; m < 4; ++m)
            af[m] = *(const bf16x8*)(As + (wr * 64 + m * 16 + lr) * 32 + kh * 8);
#pragma unroll
        for (int n = 0; n < 4; ++n)
            bfr[n] = *(const bf16x8*)(Bs + (wc * 64 + n * 16 + lr) * 32 + kh * 8);
#pragma unroll
        for (int m = 0; m < 4; ++m)
#pragma unroll
            for (int n = 0; n < 4; ++n)
                acc[m][n] = __builtin_amdgcn_mfma_f32_16x16x32_bf16(af[m], bfr[n], acc[m][n], 0, 0, 0);
        __syncthreads();
    }

#pragma unroll
    for (int m = 0; m < 4; ++m) {
        const int r0 = m0 + wr * 64 + m * 16 + kh * 4;
#pragma unroll
        for (int n = 0; n < 4; ++n) {
            const int c = n0 + wc * 64 + n * 16 + lr;
#pragma unroll
            for (int j = 0; j < 4; ++j) {
                const int r = r0 + j;
                const float v = acc[m][n][j];
                if (EPI == 0) {
                    const int b = r >> 11, sy = r & 2047, h = c >> 7, dd = c & 127;
                    ((__hip_bfloat16*)Cout)[((size_t)(b * 16 + h) * 2048 + sy) * 128 + dd] =
                        __float2bfloat16(v);
                } else if (EPI == 2) {
                    const int b = r >> 11, sy = r & 2047, h = c >> 7, dd = c & 127;
                    ((__hip_bfloat16*)Cout)[((size_t)(b * 16 + h) * 128 + dd) * 2048 + sy] =
                        __float2bfloat16(v);
                } else {
                    ((float*)Cout)[(size_t)r * 2048 + c] = v;
                }
            }
        }
    }
}

// ---------------- RoPE in-place on Q and K: [32][2048][128] ----------------
__global__ void rope_qk(__hip_bfloat16* __restrict__ Q, __hip_bfloat16* __restrict__ Kk) {
    const int row = blockIdx.x * 4 + (threadIdx.x >> 6);
    const int j = threadIdx.x & 63;
    const int s = row & 2047;
    const float inv = __expf((float)j * (-0.14391156831212787f)); // -ln(10000)/64
    float sn, c;
    __sincosf((float)s * inv, &sn, &c);
    const size_t base = (size_t)row * 128;
    float q1 = __bfloat162float(Q[base + j]);
    float q2 = __bfloat162float(Q[base + 64 + j]);
    Q[base + j]      = __float2bfloat16(q1 * c - q2 * sn);
    Q[base + 64 + j] = __float2bfloat16(q2 * c + q1 * sn);
    float k1 = __bfloat162float(Kk[base + j]);
    float k2 = __bfloat162float(Kk[base + 64 + j]);
    Kk[base + j]      = __float2bfloat16(k1 * c - k2 * sn);
    Kk[base + 64 + j] = __float2bfloat16(k2 * c + k1 * sn);
}

// ---------------- causal flash attention: swapped-QK^T in-register softmax ----------------
// Q,K: [32][2048][128] bf16. Vt: [32][128][2048] bf16 (V^T).
// Block = 4 waves = 64 q-rows (group G), shared KV range, KVBLK=32 double-buffered in LDS.
// S^T = mfma(K,Q): lane (lr,hi) holds S[q=qb+lr][kv0 + f*16 + hi*4 + j] -> row stats are
// 7 in-reg ops + 2 shfl_xor. P redistributed to PV A-fragment via 8 bpermute + 4 cndmask.
__global__ __launch_bounds__(256, 4)
void flash_part(const __hip_bfloat16* __restrict__ Q,
                const __hip_bfloat16* __restrict__ K,
                const __hip_bfloat16* __restrict__ Vt,
                __hip_bfloat16* __restrict__ AO,
                __hip_bfloat16* __restrict__ OP,
                float* __restrict__ ML)
{
    const int bh = blockIdx.x;
    const int u  = blockIdx.y;
    const int tid = threadIdx.x, w = tid >> 6, l = tid & 63;
    const int lr = l & 15, hi = l >> 4;

    int G, part, P;
    if (u < 32)      { G = 24 + (u >> 2);            part = u & 3;       P = 4; }
    else if (u < 56) { int v = u - 32; G = 16 + v/3; part = v % 3;       P = 3; }
    else if (u < 72) { int v = u - 56; G = 8 + (v>>1); part = v & 1;     P = 2; }
    else             { G = u - 72;                   part = 0;           P = 1; }
    const int nt = 2 * G + 2;
    const int t0 = (part * nt) / P, t1 = ((part + 1) * nt) / P;
    const bool split = (P > 1);
    const int qb = G * 64 + w * 16;
    const int q_own = qb + lr;

    const __hip_bfloat16* Qb = Q  + (size_t)bh * 2048 * 128;
    const __hip_bfloat16* Kb = K  + (size_t)bh * 2048 * 128;
    const __hip_bfloat16* Vb = Vt + (size_t)bh * 128 * 2048;

    __shared__ __align__(16) __hip_bfloat16 Ks[2][32 * 128];
    __shared__ __align__(16) __hip_bfloat16 Vs[2][128 * 32];

    // Q fragments (row = lr, k = kk*32 + hi*8 + j) — used as the B operand of mfma(K,Q)
    bf16x8 qf[4];
#pragma unroll
    for (int kk = 0; kk < 4; ++kk)
        qf[kk] = *(const bf16x8*)(Qb + (size_t)(qb + lr) * 128 + kk * 32 + hi * 8);

    // staging geometry (per thread, loop-invariant)
    int rK[2], cK[2], rV[2], cV[2];
#pragma unroll
    for (int i = 0; i < 2; ++i) {
        const int ci = i * 4 + w;
        rK[i] = ci * 4 + (l >> 4);                 // K tile row 0..31
        cK[i] = ((l & 15) ^ (rK[i] & 7)) * 8;      // swizzled source col (elems)
        rV[i] = ci * 16 + (l >> 2);                // V^T tile row (d) 0..127
        cV[i] = ((l & 3) ^ (rV[i] & 3)) * 8;       // swizzled source col (elems)
    }
    const int rsw7 = lr & 7, vsw3 = lr & 3;
    const int sA = lr + ((hi & 1) << 5);           // P-redistribution source lanes
    const int sB = sA + 16;
    const bool plo = (hi < 2);

#define STAGE(buf, t)                                                                        \
    {                                                                                        \
        const int kv0_ = (t) * 32;                                                           \
        _Pragma("unroll")                                                                    \
        for (int i = 0; i < 2; ++i) {                                                        \
            __builtin_amdgcn_global_load_lds(                                                \
                GLB_CAST(Kb + (size_t)(kv0_ + rK[i]) * 128 + cK[i]),                         \
                LDS_CAST(&Ks[buf][(i * 4 + w) * 512]), 16, 0, 0);                            \
            __builtin_amdgcn_global_load_lds(                                                \
                GLB_CAST(Vb + (size_t)rV[i] * 2048 + kv0_ + cV[i]),                          \
                LDS_CAST(&Vs[buf][(i * 4 + w) * 512]), 16, 0, 0);                            \
        }                                                                                    \
    }

    f32x4 o[8] = {};
    float mrow = -1e30f, lrow = 0.f;
    const float scale = 0.08838834764831845f;  // 1/sqrt(128)

    int cur = 0;
    STAGE(0, t0);
    __syncthreads();

    for (int t = t0; t < t1; ++t) {
        if (t + 1 < t1) STAGE(cur ^ 1, t + 1);
        const __hip_bfloat16* Kc = &Ks[cur][0];
        const __hip_bfloat16* Vc = &Vs[cur][0];
        const int kv0 = t * 32;

        // S^T = K Q^T: lane holds S[q=q_own][kv0 + f*16 + hi*4 + j]
        f32x4 sT[2] = {};
#pragma unroll
        for (int f = 0; f < 2; ++f)
#pragma unroll
            for (int kk = 0; kk < 4; ++kk) {
                const bf16x8 kf = *(const bf16x8*)(Kc + (f * 16 + lr) * 128 +
                                                   ((kk * 4 + hi) ^ rsw7) * 8);
                sT[f] = __builtin_amdgcn_mfma_f32_16x16x32_bf16(kf, qf[kk], sT[f], 0, 0, 0);
            }

        // scale + causal mask + row max (in-register)
        float val[8];
        float pmax = -1e30f;
#pragma unroll
        for (int f = 0; f < 2; ++f)
#pragma unroll
            for (int j = 0; j < 4; ++j) {
                const int kv = kv0 + f * 16 + hi * 4 + j;
                float v = sT[f][j] * scale;
                v = (kv > q_own) ? -1e30f : v;
                val[f * 4 + j] = v;
                pmax = fmaxf(pmax, v);
            }
        pmax = fmaxf(pmax, __shfl_xor(pmax, 16));
        pmax = fmaxf(pmax, __shfl_xor(pmax, 32));

        // defer-max (T13): rescale only when the running max grows by >8
        if (!__all(pmax <= mrow + 8.f)) {
            const float mnew = fmaxf(mrow, pmax);
            const float alpha = __expf(mrow - mnew);
            mrow = mnew;
            lrow *= alpha;
            float aj[4];
#pragma unroll
            for (int j = 0; j < 4; ++j)
                aj[j] = __shfl(alpha, (l & 48) | (hi * 4 + j), 64);
#pragma unroll
            for (int dn = 0; dn < 8; ++dn)
#pragma unroll
                for (int j = 0; j < 4; ++j) o[dn][j] *= aj[j];
        }

        // P = exp(val - mrow), row sum
        float p[8];
        float rs = 0.f;
#pragma unroll
        for (int i = 0; i < 8; ++i) { p[i] = __expf(val[i] - mrow); rs += p[i]; }
        rs += __shfl_xor(rs, 16);
        rs += __shfl_xor(rs, 32);
        lrow += rs;

        // pack P to bf16 words: wds[f*2+h] = (p[f*4+2h], p[f*4+2h+1])
        unsigned wds[4];
#pragma unroll
        for (int i = 0; i < 4; ++i)
            wds[i] = (unsigned)bf16_bits(p[i * 2]) | ((unsigned)bf16_bits(p[i * 2 + 1]) << 16);

        // redistribute to PV A-fragment: lane (lr,hi) needs P[q=qb+lr][kv0+hi*8 .. +7]
        const unsigned a0 = __shfl((int)wds[0], sA, 64), a1 = __shfl((int)wds[1], sA, 64);
        const unsigned a2 = __shfl((int)wds[2], sA, 64), a3 = __shfl((int)wds[3], sA, 64);
        const unsigned b0 = __shfl((int)wds[0], sB, 64), b1 = __shfl((int)wds[1], sB, 64);
        const unsigned b2 = __shfl((int)wds[2], sB, 64), b3 = __shfl((int)wds[3], sB, 64);
        union { unsigned u[4]; bf16x8 v; } pf;
        pf.u[0] = plo ? a0 : a2;
        pf.u[1] = plo ? a1 : a3;
        pf.u[2] = plo ? b0 : b2;
        pf.u[3] = plo ? b1 : b3;

        // PV: A = P (row=lr -> q, k = hi*8+{0..7} -> kv), B = V^T tile rows
#pragma unroll
        for (int dn = 0; dn < 8; ++dn) {
            const bf16x8 vf = *(const bf16x8*)(Vc + (dn * 16 + lr) * 32 + (hi ^ vsw3) * 8);
            o[dn] = __builtin_amdgcn_mfma_f32_16x16x32_bf16(pf.v, vf, o[dn], 0, 0, 0);
        }
        __syncthreads();   // drains this iter's STAGE (vmcnt) + all LDS reads
        cur ^= 1;
    }
#undef STAGE

    if (!split) {
        float linv[4];
#pragma unroll
        for (int j = 0; j < 4; ++j)
            linv[j] = 1.0f / __shfl(lrow, (l & 48) | (hi * 4 + j), 64);
#pragma unroll
        for (int j = 0; j < 4; ++j) {
            const int q = qb + hi * 4 + j;
            const size_t rb = ((size_t)(bh >> 4) * 2048 + q) * 2048 + (size_t)(bh & 15) * 128;
#pragma unroll
            for (int dn = 0; dn < 8; ++dn)
                AO[rb + dn * 16 + lr] = __float2bfloat16(o[dn][j] * linv[j]);
        }
    } else {
        const int base = (G < 16) ? (G - 8) * 2 : ((G < 24) ? 16 + (G - 16) * 3
                                                            : 40 + (G - 24) * 4);
        const int pidx = bh * 72 + base + part;
#pragma unroll
        for (int j = 0; j < 4; ++j) {
            const int row = w * 16 + hi * 4 + j;   // row within group, 0..63
#pragma unroll
            for (int dn = 0; dn < 8; ++dn)
                OP[((size_t)pidx * 64 + row) * 128 + dn * 16 + lr] = __float2bfloat16(o[dn][j]);
        }
        if (l < 16) {
            ML[((size_t)pidx * 64 + w * 16 + l) * 2]     = mrow;
            ML[((size_t)pidx * 64 + w * 16 + l) * 2 + 1] = lrow;
        }
    }
}

// ---------------- merge P in {2,3,4} partials per split group ----------------
__global__ void flash_merge(const __hip_bfloat16* __restrict__ OP,
                            const float* __restrict__ ML,
                            __hip_bfloat16* __restrict__ AO)
{
    const int gi = blockIdx.x % 24, bh = blockIdx.x / 24;
    const int G = 8 + gi;
    const int P = (G < 16) ? 2 : ((G < 24) ? 3 : 4);
    const int base = (G < 16) ? (G - 8) * 2 : ((G < 24) ? 16 + (G - 16) * 3
                                                        : 40 + (G - 24) * 4);
    const int pidx0 = bh * 72 + base;
    const int t = threadIdx.x, r = t >> 2, c0 = (t & 3) * 32;

    float m[4], lv[4];
    float M = -1e30f;
#pragma unroll
    for (int p = 0; p < 4; ++p) if (p < P) {
        m[p]  = ML[((size_t)(pidx0 + p) * 64 + r) * 2];
        lv[p] = ML[((size_t)(pidx0 + p) * 64 + r) * 2 + 1];
        M = fmaxf(M, m[p]);
    }
    float wgt[4];
    float den = 0.f;
#pragma unroll
    for (int p = 0; p < 4; ++p) if (p < P) {
        wgt[p] = __expf(m[p] - M);
        den += lv[p] * wgt[p];
    }
    const float inv = 1.0f / den;

    const int q = G * 64 + r;
    __hip_bfloat16* out = AO + ((size_t)(bh >> 4) * 2048 + q) * 2048 + (size_t)(bh & 15) * 128 + c0;

#pragma unroll
    for (int ch = 0; ch < 4; ++ch) {
        float acc[8] = {0.f, 0.f, 0.f, 0.f, 0.f, 0.f, 0.f, 0.f};
#pragma unroll
        for (int p = 0; p < 4; ++p) if (p < P) {
            const bf16x8 v = *(const bf16x8*)(OP + ((size_t)(pidx0 + p) * 64 + r) * 128 + c0 + ch * 8);
#pragma unroll
            for (int i = 0; i < 8; ++i) {
                __hip_bfloat16 hv;
                *(short*)&hv = v[i];
                acc[i] += __bfloat162float(hv) * wgt[p];
            }
        }
        union { unsigned short us[8]; bf16x8 v; } rr;
#pragma unroll
        for (int i = 0; i < 8; ++i) rr.us[i] = bf16_bits(acc[i] * inv);
        *(bf16x8*)(out + ch * 8) = rr.v;
    }
}

extern "C" void kernel_launch(void* const* d_in, const int* in_sizes, int n_in,
                              void* d_out, int out_size, void* d_ws, size_t ws_size,
                              hipStream_t stream) {
    (void)in_sizes; (void)n_in; (void)out_size; (void)ws_size;
    const float* x  = (const float*)d_in[0];
    const float* Wq = (const float*)d_in[1];
    const float* Wk = (const float*)d_in[2];
    const float* Wv = (const float*)d_in[3];
    const float* Wo = (const float*)d_in[4];

    char* p = (char*)d_ws;
    auto carve = [&](size_t bytes) -> char* {
        char* r = p;
        p += (bytes + 255) & ~(size_t)255;
        return r;
    };
    __hip_bfloat16* xb  = (__hip_bfloat16*)carve(4096ull * 2048 * 2);  // reused as AO
    __hip_bfloat16* Wqb = (__hip_bfloat16*)carve(2048ull * 2048 * 2);
    __hip_bfloat16* Wkb = (__hip_bfloat16*)carve(2048ull * 2048 * 2);
    __hip_bfloat16* Wvb = (__hip_bfloat16*)carve(2048ull * 2048 * 2);
    __hip_bfloat16* Wob = (__hip_bfloat16*)carve(2048ull * 2048 * 2);
    __hip_bfloat16* Qb  = (__hip_bfloat16*)carve(32ull * 2048 * 128 * 2);
    __hip_bfloat16* Kb  = (__hip_bfloat16*)carve(32ull * 2048 * 128 * 2);
    __hip_bfloat16* Vtb = (__hip_bfloat16*)carve(32ull * 128 * 2048 * 2);
    __hip_bfloat16* OPb = (__hip_bfloat16*)carve(32ull * 72 * 64 * 128 * 2);  // partial O
    float*          MLb = (float*)carve(32ull * 72 * 64 * 2 * 4);             // partial m,l

    cvt_f32_bf16<<<4096, 256, 0, stream>>>(x,  xb,  4096 * 2048);
    cvt_f32_bf16<<<2048, 256, 0, stream>>>(Wq, Wqb, 2048 * 2048);
    cvt_f32_bf16<<<2048, 256, 0, stream>>>(Wk, Wkb, 2048 * 2048);
    cvt_f32_bf16<<<2048, 256, 0, stream>>>(Wv, Wvb, 2048 * 2048);
    cvt_f32_bf16<<<2048, 256, 0, stream>>>(Wo, Wob, 2048 * 2048);

    dim3 gg(32, 16);
    gemm_bt<0><<<gg, 256, 0, stream>>>(xb, Wqb, Qb);
    gemm_bt<0><<<gg, 256, 0, stream>>>(xb, Wkb, Kb);
    gemm_bt<2><<<gg, 256, 0, stream>>>(xb, Wvb, Vtb);

    rope_qk<<<16384, 256, 0, stream>>>(Qb, Kb);

    flash_part<<<dim3(32, 80), 256, 0, stream>>>(Qb, Kb, Vtb, xb /* AO */, OPb, MLb);
    flash_merge<<<768, 256, 0, stream>>>(OPb, MLb, xb /* AO */);

    gemm_bt<1><<<gg, 256, 0, stream>>>(xb, Wob, (float*)d_out);
}